// Round 2
// baseline (218.930 us; speedup 1.0000x reference)
//
#include <hip/hip_runtime.h>
#include <math.h>

#define L2E 1.4426950408889634f
#define HSTR 136   // h LDS row stride (bf16 elems): 272B, 16B-aligned, even bank spread
#define PRS 16     // pbuf row stride (floats) per column

typedef __bf16 bf16x8 __attribute__((ext_vector_type(8)));
typedef float  f32x4  __attribute__((ext_vector_type(4)));

// sig2(y) = 1/(1+2^-y)  == sigmoid(x) when y = x*log2(e)
__device__ __forceinline__ float sig2(float y) {
    return __builtin_amdgcn_rcpf(1.0f + __builtin_amdgcn_exp2f(-y));
}

// ---------------- prep: stats LUT + zero accumulators + rank-1 input vectors ----------------
// grid: 65 blocks x 512 threads. Blocks 0..63: Avec/Bvec (one wave per row of W_ih).
// Block 64: normalization stats LUT + zeroing fc_sum/hs_bar.
__global__ void prep_kernel(const float* __restrict__ numbers,
                            const float* __restrict__ w_num,
                            const float* __restrict__ b_num,
                            const float* __restrict__ W_ih,
                            const float* __restrict__ b_ih,
                            const float* __restrict__ b_hh,
                            float* __restrict__ ws_base) {
    float* fc_hs    = ws_base;        // 256 floats (fc_sum + hs_bar)
    float* mean_lut = ws_base + 256;  // 100
    float* inv_lut  = ws_base + 356;  // 100
    float* Avec     = ws_base + 456;  // 512
    float* Bvec     = ws_base + 968;  // 512

    if (blockIdx.x == 64) {
        __shared__ float sx[100];
        int tid = threadIdx.x;
        if (tid < 256) fc_hs[tid] = 0.0f;
        if (tid < 100) sx[tid] = numbers[tid];
        __syncthreads();
        if (tid < 100) {
            float s = 0.f, ss = 0.f;
            for (int j = 0; j <= tid; ++j) { float v = sx[j]; s += v; ss += v * v; }
            float cap  = (float)(tid + 1);
            float mean = s / cap;
            float var  = ss / cap - mean * mean;
            if (var < 0.f) var = 0.f;
            float sd = sqrtf(var);
            float inv = (cap > 3.0f && sd > 1e-8f) ? (1.0f / sd) : 1.0f;
            mean_lut[tid] = mean;
            inv_lut[tid]  = inv;
        }
        return;
    }
    // one wave per output row j of the rank-1 reduction
    int j    = blockIdx.x * 8 + (threadIdx.x >> 6);   // 0..511
    int lane = threadIdx.x & 63;
    const float* row = W_ih + j * 256 + 128;
    float r1 = row[lane], r2 = row[lane + 64];
    float a = r1 * w_num[lane] + r2 * w_num[lane + 64];
    float b = r1 * b_num[lane] + r2 * b_num[lane + 64];
    #pragma unroll
    for (int off = 32; off >= 1; off >>= 1) {
        a += __shfl_xor(a, off);
        b += __shfl_xor(b, off);
    }
    if (lane == 0) {
        float s = (j >= 256 && j < 384) ? (2.0f * L2E) : L2E;  // g gate gets 2*log2e
        Avec[j] = a * s;
        Bvec[j] = (b + b_ih[j] + b_hh[j]) * s;
    }
}

// ---------------- main: 128-step LSTM, 16 rows/block, 16 waves gate-split ----------------
// waves 0..7  ("low"):  gates i,g for col tile m0=(w&7)*16 -> p = sig(i)*tanh(g) -> pbuf
// waves 8..15 ("high"): gates f,o, own c state, c2 = sf*c + p, h = so*tanh(c2) -> hbuf
__global__ __launch_bounds__(1024, 4) void lstm_kernel(
        const float* __restrict__ numbers, const float* __restrict__ W_hh,
        const float* __restrict__ W_fh,    const float* __restrict__ b_fh,
        const float* __restrict__ mean_lut, const float* __restrict__ inv_lut,
        const float* __restrict__ Avec,     const float* __restrict__ Bvec,
        float* __restrict__ fc_sum, float* __restrict__ hs_bar) {
    __shared__ unsigned short hbuf[2][16 * HSTR];   // h state, bf16, [row][col]
    __shared__ float xls[128 * 16];                 // normalized x, [t][row]
    __shared__ float pbuf[128 * PRS];               // p = sig(i)*tanh(g), [col][row]

    const int tid  = threadIdx.x;
    const int lane = tid & 63;
    const int wave = tid >> 6;        // 0..15
    const bool low = wave < 8;
    const int quad = lane >> 4;       // 0..3
    const int lcol = lane & 15;
    const int m0   = (wave & 7) * 16; // column tile within a gate
    const int r0   = blockIdx.x * 16; // global batch row base

    // ---- load + normalize x into LDS [t][row] ----
    for (int i = tid; i < 16 * 128; i += 1024) {
        int row = i >> 7;
        int t   = i & 127;
        int flat = (r0 + row) * 128 + t;
        int ii = (flat < 100) ? flat : 99;
        float v = numbers[flat];
        xls[t * 16 + row] = (v - mean_lut[ii]) * inv_lut[ii];
    }
    for (int i = tid; i < 16 * HSTR; i += 1024) hbuf[0][i] = 0;

    // ---- persistent W_hh B-fragments (bf16, log2e-folded) ----
    const int g0 = low ? 0 : 1;       // i | f
    const int g1 = low ? 2 : 3;       // g | o
    const float s0 = L2E;
    const float s1 = low ? (2.0f * L2E) : L2E;
    bf16x8 bf[2][4];
    #pragma unroll
    for (int gi = 0; gi < 2; ++gi) {
        int g = gi ? g1 : g0;
        float sc = gi ? s1 : s0;
        #pragma unroll
        for (int kk = 0; kk < 4; ++kk) {
            const float* p = W_hh + (g * 128 + m0 + lcol) * 128 + kk * 32 + quad * 8;
            f32x4 w0 = *(const f32x4*)p;
            f32x4 w1 = *(const f32x4*)(p + 4);
            bf16x8 bt;
            #pragma unroll
            for (int q = 0; q < 4; ++q) {
                bt[q]     = (__bf16)(w0[q] * sc);
                bt[q + 4] = (__bf16)(w1[q] * sc);
            }
            bf[gi][kk] = bt;
        }
    }
    float ag[2], bg[2];
    ag[0] = Avec[g0 * 128 + m0 + lcol];  bg[0] = Bvec[g0 * 128 + m0 + lcol];
    ag[1] = Avec[g1 * 128 + m0 + lcol];  bg[1] = Bvec[g1 * 128 + m0 + lcol];

    float c[4]  = {0.f, 0.f, 0.f, 0.f};
    float hf[4] = {0.f, 0.f, 0.f, 0.f};
    __syncthreads();

    for (int t = 0; t < 128; ++t) {
        const unsigned short* hin = hbuf[t & 1];
        unsigned short* hout = hbuf[(t + 1) & 1];
        // A-fragments of h(t-1)
        bf16x8 af[4];
        #pragma unroll
        for (int kk = 0; kk < 4; ++kk)
            af[kk] = *(const bf16x8*)(const void*)(hin + lcol * HSTR + kk * 32 + quad * 8);
        f32x4 xq = *(const f32x4*)(const void*)(xls + t * 16 + quad * 4);
        // two gate pre-activation tiles (log2e domain)
        f32x4 acc[2];
        #pragma unroll
        for (int gi = 0; gi < 2; ++gi) {
            f32x4 a0;
            #pragma unroll
            for (int r = 0; r < 4; ++r) a0[r] = xq[r] * ag[gi] + bg[gi];
            #pragma unroll
            for (int kk = 0; kk < 4; ++kk)
                a0 = __builtin_amdgcn_mfma_f32_16x16x32_bf16(af[kk], bf[gi][kk], a0, 0, 0, 0);
            acc[gi] = a0;
        }
        float sf[4], so[4];
        if (low) {
            f32x4 pv;
            #pragma unroll
            for (int r = 0; r < 4; ++r) {
                float si = sig2(acc[0][r]);
                float tg = 2.0f * sig2(acc[1][r]) - 1.0f;
                pv[r] = si * tg;
            }
            *(f32x4*)(pbuf + (m0 + lcol) * PRS + quad * 4) = pv;
        } else {
            #pragma unroll
            for (int r = 0; r < 4; ++r) {
                sf[r] = sig2(acc[0][r]);
                so[r] = sig2(acc[1][r]);
            }
        }
        __syncthreads();   // p visible
        if (!low) {
            f32x4 pv = *(const f32x4*)(const void*)(pbuf + (m0 + lcol) * PRS + quad * 4);
            #pragma unroll
            for (int r = 0; r < 4; ++r) {
                float c2 = sf[r] * c[r] + pv[r];
                c[r] = c2;
                float th = 2.0f * sig2(c2 * (2.0f * L2E)) - 1.0f;
                float h = so[r] * th;
                hf[r] = h;
                hout[(quad * 4 + r) * HSTR + m0 + lcol] =
                    __builtin_bit_cast(unsigned short, (__bf16)h);
            }
        }
        __syncthreads();   // h(t) visible
    }

    if (!low) {
        // hs_bar partial (final h held by high waves)
        float v = hf[0] + hf[1] + hf[2] + hf[3];
        v += __shfl_xor(v, 16);
        v += __shfl_xor(v, 32);
        if (lane < 16) atomicAdd(&hs_bar[m0 + lane], v);
        // f_g = sig(h @ W_fh^T + b_fh) (log2e-folded); fc partial
        f32x4 facc;
        {
            float bb = b_fh[m0 + lcol] * L2E;
            #pragma unroll
            for (int r = 0; r < 4; ++r) facc[r] = bb;
        }
        #pragma unroll
        for (int kk = 0; kk < 4; ++kk) {
            bf16x8 afr = *(const bf16x8*)(const void*)(hbuf[0] + lcol * HSTR + kk * 32 + quad * 8);
            const float* p = W_fh + (m0 + lcol) * 128 + kk * 32 + quad * 8;
            f32x4 w0 = *(const f32x4*)p;
            f32x4 w1 = *(const f32x4*)(p + 4);
            bf16x8 wt;
            #pragma unroll
            for (int q = 0; q < 4; ++q) {
                wt[q]     = (__bf16)(w0[q] * L2E);
                wt[q + 4] = (__bf16)(w1[q] * L2E);
            }
            facc = __builtin_amdgcn_mfma_f32_16x16x32_bf16(afr, wt, facc, 0, 0, 0);
        }
        float fcv = 0.f;
        #pragma unroll
        for (int r = 0; r < 4; ++r) fcv += sig2(facc[r]) * c[r];
        fcv += __shfl_xor(fcv, 16);
        fcv += __shfl_xor(fcv, 32);
        if (lane < 16) atomicAdd(&fc_sum[m0 + lane], fcv);
    }
}

// ---------------- epilogue: root Tree-LSTM cell + output projection ----------------
__global__ void finalize_kernel(const float* __restrict__ fc_sum,
                                const float* __restrict__ hs_bar,
                                const float* __restrict__ W_iouh,
                                const float* __restrict__ b_iouh,
                                const float* __restrict__ W_lout,
                                const float* __restrict__ b_lout,
                                float* __restrict__ out) {
    __shared__ float hsb[128], iou[384], hfin[128];
    int tid = threadIdx.x;
    if (tid < 128) hsb[tid] = hs_bar[tid];
    __syncthreads();
    if (tid < 384) {
        float s = b_iouh[tid];
        const f32x4* row = (const f32x4*)(W_iouh + tid * 128);
        #pragma unroll 8
        for (int m = 0; m < 32; ++m) {
            f32x4 w = row[m];
            s += w[0] * hsb[4*m] + w[1] * hsb[4*m+1] + w[2] * hsb[4*m+2] + w[3] * hsb[4*m+3];
        }
        iou[tid] = s;
    }
    __syncthreads();
    if (tid < 128) {
        float i = iou[tid], o = iou[128 + tid], u = iou[256 + tid];
        float cf = sig2(i * L2E) * (2.0f * sig2(u * 2.0f * L2E) - 1.0f) + fc_sum[tid];
        out[tid] = cf;
        hfin[tid] = sig2(o * L2E) * (2.0f * sig2(cf * 2.0f * L2E) - 1.0f);
    }
    __syncthreads();
    if (tid < 128) {
        float s = b_lout[tid];
        const f32x4* row = (const f32x4*)(W_lout + tid * 128);
        #pragma unroll 8
        for (int m = 0; m < 32; ++m) {
            f32x4 w = row[m];
            s += w[0] * hfin[4*m] + w[1] * hfin[4*m+1] + w[2] * hfin[4*m+2] + w[3] * hfin[4*m+3];
        }
        out[128 + tid] = s;
    }
}

extern "C" void kernel_launch(void* const* d_in, const int* in_sizes, int n_in,
                              void* d_out, int out_size, void* d_ws, size_t ws_size,
                              hipStream_t stream) {
    const float* numbers = (const float*)d_in[0];
    const float* w_num   = (const float*)d_in[1];
    const float* b_num   = (const float*)d_in[2];
    const float* W_ih    = (const float*)d_in[3];
    const float* W_hh    = (const float*)d_in[4];
    const float* b_ih    = (const float*)d_in[5];
    const float* b_hh    = (const float*)d_in[6];
    const float* W_fh    = (const float*)d_in[7];
    const float* b_fh    = (const float*)d_in[8];
    const float* W_iouh  = (const float*)d_in[9];
    const float* b_iouh  = (const float*)d_in[10];
    const float* W_lout  = (const float*)d_in[11];
    const float* b_lout  = (const float*)d_in[12];
    float* out = (float*)d_out;

    float* ws       = (float*)d_ws;
    float* fc_sum   = ws;         // 128
    float* hs_bar   = ws + 128;   // 128
    float* mean_lut = ws + 256;   // 100
    float* inv_lut  = ws + 356;   // 100
    float* Avec     = ws + 456;   // 512
    float* Bvec     = ws + 968;   // 512

    prep_kernel<<<65, 512, 0, stream>>>(numbers, w_num, b_num, W_ih, b_ih, b_hh, ws);
    lstm_kernel<<<256, 1024, 0, stream>>>(numbers, W_hh, W_fh, b_fh,
                                          mean_lut, inv_lut, Avec, Bvec, fc_sum, hs_bar);
    finalize_kernel<<<1, 384, 0, stream>>>(fc_sum, hs_bar, W_iouh, b_iouh, W_lout, b_lout, out);
}